// Round 16
// baseline (703.667 us; speedup 1.0000x reference)
//
#include <hip/hip_runtime.h>
#include <cstdint>
#include <cstddef>

#define IN_F  4096
#define OUT_F 16384
#define NROWS 8192   // 2*4096 tokens
#define NKT   64     // 64B K-tiles (producer layout granularity)
#define NKT2  32     // 128B K-tiles (GEMM loop granularity)

#define NTBLK 16384  // transpose blocks (256 n-tiles x 64 k-tiles)
#define NQBLK 1024   // quant blocks (8 rows each)

typedef __attribute__((ext_vector_type(4)))  int int32x4;
typedef __attribute__((ext_vector_type(16))) int int32x16;

// async global->LDS, 16B/lane (dest = wave-uniform base, HW adds lane*16)
__device__ __forceinline__ void gload_lds16(const void* g, void* s) {
    __builtin_amdgcn_global_load_lds((const __attribute__((address_space(1))) void*)g,
                                     (__attribute__((address_space(3))) void*)s,
                                     16, 0, 0);
}

// ---------------------------------------------------------------------------
// Layouts (fragment-major, shared by producers and GEMM staging):
//   xqS: [mtile 32][kt 64][c 4][row 256][16B]   (64B tiles; 2 consecutive = 32KB 128B tile)
//   wtS: [ntile 64][kt 64][c 4][col 256][16B]
// ---------------------------------------------------------------------------

// Fused prologue: blocks [0, NTBLK) transpose W (register 4x4 byte-transpose);
// blocks [NTBLK, NTBLK+NQBLK) quantize x. Whole blocks per branch.
__global__ __launch_bounds__(256) void prep_kernel(const int* __restrict__ w,
                                                   const float* __restrict__ x,
                                                   uint8_t* __restrict__ wtS,
                                                   uint8_t* __restrict__ xqS,
                                                   float* __restrict__ xs) {
    __shared__ uint32_t tl[64][17];   // pad 17: bank-conflict-free
    const int b = blockIdx.x;
    const int t = threadIdx.x;

    if (b < NTBLK) {
        const int nb = (b & 255) * 64;
        const int kt = b >> 8;          // K-tile index 0..63
        const int r  = t >> 4;          // k-quad 0..15
        const int c  = t & 15;          // n-quad 0..15

        const int* src = w + (size_t)(kt * 64 + 4 * r) * OUT_F + nb + 4 * c;
        uint32_t wk[4];
#pragma unroll
        for (int i = 0; i < 4; ++i) {
            int4 u = *reinterpret_cast<const int4*>(src + (size_t)i * OUT_F);
            wk[i] = (uint32_t)(u.x & 255) | ((uint32_t)(u.y & 255) << 8)
                  | ((uint32_t)(u.z & 255) << 16) | ((uint32_t)u.w << 24);
        }
#pragma unroll
        for (int j = 0; j < 4; ++j) {
            uint32_t v = ((wk[0] >> (8 * j)) & 255)
                       | (((wk[1] >> (8 * j)) & 255) << 8)
                       | (((wk[2] >> (8 * j)) & 255) << 16)
                       | (((wk[3] >> (8 * j)) & 255) << 24);
            tl[4 * c + j][r] = v;
        }
        __syncthreads();

        const int n  = t >> 2;          // output n-row 0..63
        const int qq = t & 3;           // 16B k-chunk 0..3
        uint4 o;
        o.x = tl[n][4 * qq];
        o.y = tl[n][4 * qq + 1];
        o.z = tl[n][4 * qq + 2];
        o.w = tl[n][4 * qq + 3];
        const int ntile = nb >> 8;
        const int colg  = (nb & 255) + n;
        *reinterpret_cast<uint4*>(wtS + (((size_t)ntile * NKT + kt) * 4 + qq) * 4096 + colg * 16) = o;
    } else {
        const int qb = b - NTBLK;
        const int wv = t >> 6, l = t & 63;
        const int half = l >> 5, lh = l & 31;
        const int m = qb * 8 + wv * 2 + half;
        const float* xr = x + (size_t)m * IN_F;

        float am = 0.0f;
#pragma unroll 8
        for (int jj = 0; jj < 32; ++jj) {
            float4 v = reinterpret_cast<const float4*>(xr)[jj * 32 + lh];
            am = fmaxf(am, fmaxf(fmaxf(fabsf(v.x), fabsf(v.y)),
                                 fmaxf(fabsf(v.z), fabsf(v.w))));
        }
#pragma unroll
        for (int off = 16; off; off >>= 1) am = fmaxf(am, __shfl_xor(am, off));

        const float scale = fmaxf(am / 127.0f, 1e-12f);
        if (lh == 0) xs[m] = scale;

        const int mtile = m >> 8, mrow = m & 255;
        uint8_t* ob = xqS + (size_t)mtile * (NKT * 16384) + (size_t)mrow * 16;
#pragma unroll
        for (int j = 0; j < 8; ++j) {
            const int k0 = lh * 128 + j * 16;
            const float4* vp = reinterpret_cast<const float4*>(xr + k0);
            uint4 pk;
            uint32_t* pp = reinterpret_cast<uint32_t*>(&pk);
#pragma unroll
            for (int q = 0; q < 4; ++q) {
                float4 v = vp[q];
                float r0 = fminf(127.f, fmaxf(-128.f, rintf(v.x / scale)));
                float r1 = fminf(127.f, fmaxf(-128.f, rintf(v.y / scale)));
                float r2 = fminf(127.f, fmaxf(-128.f, rintf(v.z / scale)));
                float r3 = fminf(127.f, fmaxf(-128.f, rintf(v.w / scale)));
                pp[q] = ((uint32_t)((int)r0 & 255)) | ((uint32_t)((int)r1 & 255) << 8)
                      | ((uint32_t)((int)r2 & 255) << 16) | ((uint32_t)((int)r3 & 255) << 24);
            }
            const int ktk = k0 >> 6;
            const int c   = (k0 >> 4) & 3;
            *reinterpret_cast<uint4*>(ob + ((size_t)ktk * 4 + c) * 4096) = pk;
        }
    }
}

// ---------------------------------------------------------------------------
// Kernel 3: int8 GEMM — round-8 champion with BK=128: same 256x256 tile,
// 8 waves (2Mx4N), same reg-dbuf read/MFMA interleave, but the per-tile
// {lgkmcnt(0) + vmcnt + s_barrier} now amortizes over 128B of K (4 MFMA
// clusters) instead of 64B (2 clusters) — sync rate halves, overlap pattern
// preserved. Double-buffered 2x32KB A + 2x32KB B (128KB). Depth-1 staging:
// issue-to-wait distance = full 128B tile (~4900cyc >> 900cyc HBM latency).
// ---------------------------------------------------------------------------
__global__ __launch_bounds__(512, 2) void gemm_kernel(const uint8_t* __restrict__ xqS,
                                                      const uint8_t* __restrict__ wtS,
                                                      const float* __restrict__ xs,
                                                      const float* __restrict__ wsc,
                                                      const float* __restrict__ bias,
                                                      float* __restrict__ out) {
    extern __shared__ uint8_t lds[];
    uint8_t* ldsA = lds;            // 2 bufs * 32KB
    uint8_t* ldsB = lds + 65536;    // 2 bufs * 32KB

    const int t    = threadIdx.x;
    const int lane = t & 63;
    const int wid  = t >> 6;
    const int wm   = wid >> 2, wn = wid & 3;   // wave tile: 128 rows x 64 cols

    // XCD-aware mapping (round 8: FETCH 1.08GB -> 394MB):
    const int xcd = blockIdx.x & 7;
    const int i   = blockIdx.x >> 3;           // 0..255 local on this XCD
    const int mt  = xcd * 4 + (i & 3);         // 0..31
    const int nt  = i >> 2;                    // 0..63

    const uint8_t* aBase = xqS + (size_t)mt * (NKT * 16384);
    const uint8_t* bBase = wtS + (size_t)nt * (NKT * 16384);
    const int t16  = t * 16;
    const int wofs = wid * 1024;

    const int aRd0 = (lane >> 5) * 4096 + wm * 2048 + (lane & 31) * 16;
    const int bRd0 = (lane >> 5) * 4096 + wn * 1024 + (lane & 31) * 16;

    int32x16 acc[4][2] = {};
    int32x4 af0[4], bf0[2], af1[4], bf1[2];

#define RD_F(AF, BF, OFS)                                                             \
    {                                                                                 \
        _Pragma("unroll")                                                             \
        for (int mr = 0; mr < 4; ++mr)                                                \
            AF[mr] = *reinterpret_cast<const int32x4*>(ldsA + (OFS) + aRd0 + mr * 512); \
        _Pragma("unroll")                                                             \
        for (int nr = 0; nr < 2; ++nr)                                                \
            BF[nr] = *reinterpret_cast<const int32x4*>(ldsB + (OFS) + bRd0 + nr * 512); \
    }
#define MFMA_F(AF, BF)                                                                \
    {                                                                                 \
        __builtin_amdgcn_s_setprio(1);                                                \
        _Pragma("unroll")                                                             \
        for (int mr = 0; mr < 4; ++mr)                                                \
            _Pragma("unroll")                                                         \
            for (int nr = 0; nr < 2; ++nr)                                            \
                acc[mr][nr] = __builtin_amdgcn_mfma_i32_32x32x32_i8(AF[mr], BF[nr], acc[mr][nr], 0, 0, 0); \
        __builtin_amdgcn_s_setprio(0);                                                \
    }

    // prologue: stage 128B-tile 0 (A: 4 passes of 8KB, B: 4 passes)
#pragma unroll
    for (int p = 0; p < 4; ++p) {
        gload_lds16(aBase + p * 8192 + t16, ldsA + p * 8192 + wofs);
        gload_lds16(bBase + p * 8192 + t16, ldsB + p * 8192 + wofs);
    }
    asm volatile("s_waitcnt vmcnt(0)" ::: "memory");
    __builtin_amdgcn_s_barrier();
    __builtin_amdgcn_sched_barrier(0);
    RD_F(af0, bf0, 0)                       // (tile 0, ksub 0) -> f0

    for (int kt2 = 0; kt2 < NKT2; ++kt2) {
        const int qb = (kt2 & 1) * 32768;
        const int qn = ((kt2 + 1) & 1) * 32768;

        // stage tile kt2+1 into the other buffer (its readers — tile kt2-1 —
        // drained via lgkmcnt(0) before the previous barrier)
        if (kt2 < NKT2 - 1) {
            const size_t srcn = (size_t)(kt2 + 1) * 32768;
#pragma unroll
            for (int p = 0; p < 4; ++p) {
                gload_lds16(aBase + srcn + p * 8192 + t16, ldsA + qn + p * 8192 + wofs);
                gload_lds16(bBase + srcn + p * 8192 + t16, ldsB + qn + p * 8192 + wofs);
            }
        }

        // 4 sub-phases, reg-dbuf: reads(s+1) issue before MFMA(s)
        RD_F(af1, bf1, qb + 8192)           // ksub 1
        MFMA_F(af0, bf0)                    // ksub 0
        RD_F(af0, bf0, qb + 16384)          // ksub 2
        MFMA_F(af1, bf1)                    // ksub 1
        RD_F(af1, bf1, qb + 24576)          // ksub 3
        MFMA_F(af0, bf0)                    // ksub 2

        if (kt2 < NKT2 - 1) {
            // single sync point per 128B tile:
            asm volatile("s_waitcnt lgkmcnt(0)" ::: "memory");   // WAR: my reads done
            asm volatile("s_waitcnt vmcnt(0)" ::: "memory");     // staged tile landed
            __builtin_amdgcn_s_barrier();
            __builtin_amdgcn_sched_barrier(0);
            RD_F(af0, bf0, qn)              // (tile kt2+1, ksub 0) -> f0
        }
        MFMA_F(af1, bf1)                    // ksub 3 (reads drained above)
    }

    // epilogue: C/D 32x32 layout: col = lane&31, row = (g&3)+8*(g>>2)+4*(lane>>5)
    const int row0 = mt * 256 + wm * 128;
    const int col0 = nt * 256 + wn * 64;
#pragma unroll
    for (int mr = 0; mr < 4; ++mr) {
        const int rbase = row0 + mr * 32 + 4 * (lane >> 5);
        float xsv[16];
#pragma unroll
        for (int g = 0; g < 16; ++g)
            xsv[g] = xs[rbase + (g & 3) + 8 * (g >> 2)];
#pragma unroll
        for (int nr = 0; nr < 2; ++nr) {
            const int n = col0 + nr * 32 + (lane & 31);
            const float ws_n = wsc[n];
            const float b_n  = bias[n];
#pragma unroll
            for (int g = 0; g < 16; ++g) {
                const int m = rbase + (g & 3) + 8 * (g >> 2);
                out[(size_t)m * OUT_F + n] = (float)acc[mr][nr][g] * xsv[g] * ws_n + b_n;
            }
        }
    }
}

// ---------------------------------------------------------------------------
extern "C" void kernel_launch(void* const* d_in, const int* in_sizes, int n_in,
                              void* d_out, int out_size, void* d_ws, size_t ws_size,
                              hipStream_t stream) {
    const float* x    = (const float*)d_in[0];
    const int*   wq   = (const int*)d_in[1];     // int8 pushed as int32 [4096][16384]
    const float* wsc  = (const float*)d_in[2];
    const float* bias = (const float*)d_in[3];
    float* out = (float*)d_out;

    uint8_t* ws  = (uint8_t*)d_ws;
    uint8_t* wtS = ws;                                               // 64 MiB
    uint8_t* xqS = ws + (size_t)IN_F * OUT_F;                        // 32 MiB
    float*   xs  = (float*)(ws + (size_t)IN_F * OUT_F + (size_t)NROWS * IN_F);

    (void)hipFuncSetAttribute((const void*)gemm_kernel,
                              hipFuncAttributeMaxDynamicSharedMemorySize, 131072);

    prep_kernel<<<NTBLK + NQBLK, 256, 0, stream>>>(wq, x, wtS, xqS, xs);
    gemm_kernel<<<(NROWS / 256) * (OUT_F / 256), 512, 131072, stream>>>(xqS, wtS, xs, wsc, bias, out);
}